// Round 8
// baseline (1417.063 us; speedup 1.0000x reference)
//
#include <hip/hip_runtime.h>
#include <cstdint>
#include <cstddef>

#define Bsz 8
#define Ssz 256
#define Msz 2048
#define SPLITK 8
#define REP 32

typedef _Float16 f16x8 __attribute__((ext_vector_type(8)));
typedef _Float16 f16x4 __attribute__((ext_vector_type(4)));
typedef float f32x16 __attribute__((ext_vector_type(16)));

// ---------------- pack (x32 rep for profiling visibility) ----------------
__global__ __launch_bounds__(256) void k_pack(
    const float* __restrict__ W1, const float* __restrict__ W2,
    const float* __restrict__ dep, const float* __restrict__ tok,
    _Float16* __restrict__ W1pk, _Float16* __restrict__ W2pk,
    _Float16* __restrict__ dpk,  _Float16* __restrict__ tokT)
{
  __shared__ float tile[32][33];
  const int bx = blockIdx.x, tid = threadIdx.x;
  for (int rep = 0; rep < REP; ++rep) {
    asm volatile("" ::: "memory");
    if (bx < 768) {
      const bool isW1 = bx < 256;
      const int idx = (isW1 ? bx : bx - 256) * 256 + tid;
      const int r  = idx & 31;
      const int pb = (idx >> 5) & 3;
      const int kc = idx >> 7;
      const float* src = (isW1 ? W1 : W2) + (size_t)(pb * 32 + r) * (isW1 ? 8192 : 16384) + kc * 16;
      const float4* s4 = (const float4*)src;
      float4 u0 = s4[0], u1 = s4[1], u2 = s4[2], u3 = s4[3];
      f16x8 lo = {(_Float16)u0.x,(_Float16)u0.y,(_Float16)u0.z,(_Float16)u0.w,
                  (_Float16)u1.x,(_Float16)u1.y,(_Float16)u1.z,(_Float16)u1.w};
      f16x8 hi = {(_Float16)u2.x,(_Float16)u2.y,(_Float16)u2.z,(_Float16)u2.w,
                  (_Float16)u3.x,(_Float16)u3.y,(_Float16)u3.z,(_Float16)u3.w};
      _Float16* dst = (isW1 ? W1pk : W2pk) + ((size_t)(kc * 4 + pb) * 64) * 8;
      *(f16x8*)(dst + (size_t)r * 8)        = lo;
      *(f16x8*)(dst + (size_t)(32 + r) * 8) = hi;
    } else if (bx < 832) {
      const int idx = (bx - 768) * 256 + tid;
      const int m = idx & 2047, pc = idx >> 11;
      const float4* s4 = (const float4*)(dep + (size_t)m * 64 + pc * 8);
      float4 u0 = s4[0], u1 = s4[1];
      f16x8 v = {(_Float16)u0.x,(_Float16)u0.y,(_Float16)u0.z,(_Float16)u0.w,
                 (_Float16)u1.x,(_Float16)u1.y,(_Float16)u1.z,(_Float16)u1.w};
      *(f16x8*)(dpk + ((size_t)pc * Msz + m) * 8) = v;
    } else {
      const int q = bx - 832;
      const int mt = q >> 2, tt = q & 3;
      const int tx = tid & 31, ty = tid >> 5;
      __syncthreads();
      for (int yy = ty; yy < 32; yy += 8)
        tile[yy][tx] = tok[(size_t)(mt * 32 + yy) * 128 + tt * 32 + tx];
      __syncthreads();
      for (int yy = ty; yy < 32; yy += 8)
        tokT[(size_t)(tt * 32 + yy) * Msz + mt * 32 + tx] = (_Float16)tile[tx][yy];
    }
  }
}

// ---------------- MFMA GEMM: 64m x 128n tile, 8 waves (2m x 4n), SPLITK=8 ----------------
// wave tile 32m x 32n (one acc). A hoisted across t-loop.
// mfma_f32_32x32x16_f16: A row=lane&31, k=(lane>>5)*8+j; B col same; D col=lane&31,
// row=(reg&3)+8*(reg>>2)+4*(lane>>5).
template<int LGDV, int KC>
__global__ __launch_bounds__(512) void k_gemm(
    const _Float16* __restrict__ Apk,   // [DV/8][Msz][8]
    const _Float16* __restrict__ Wpk,   // [Ktot/16][4][64][8]
    const _Float16* __restrict__ tokT,  // [128][Msz]
    float* __restrict__ part)           // [SPLITK][Msz][128]
{
  constexpr int DV  = 1 << LGDV;
  constexpr int NT  = KC >> LGDV;      // 16
  constexpr int NKS = DV >> 4;         // 4 (phase1) or 8 (phase2)

  const int tid  = threadIdx.x;
  const int lane = tid & 63;
  const int wv   = tid >> 6;           // 0..7
  const int wm   = wv >> 2;            // m-half (32 rows)
  const int wo   = wv & 3;             // n-quarter (32 cols)
  const int l31  = lane & 31;
  const int lg   = lane >> 5;
  const int id   = blockIdx.x;
  const int sk   = id & 7;             // same-XCD blocks share sk -> W slice L2-resident
  const int mb   = id >> 3;            // 0..31
  const int m0   = mb * 64;
  const int mrow0 = m0 + wm * 32 + l31;

  for (int rep = 0; rep < REP; ++rep) {
    asm volatile("" ::: "memory");
    f16x8 a[NKS];
    #pragma unroll
    for (int ks = 0; ks < NKS; ++ks)
      a[ks] = *(const f16x8*)(Apk + ((size_t)(ks * 2 + lg) * Msz + mrow0) * 8);

    f32x16 acc = {};
    const int t0 = sk * NT;

    #pragma unroll 1
    for (int tg = 0; tg < NT; ++tg) {
      const int t = t0 + tg;
      const _Float16 ta = tokT[(size_t)t * Msz + mrow0];
      const f16x8 tav = {ta,ta,ta,ta,ta,ta,ta,ta};
      const int kcBase = sk * (KC >> 4) + tg * NKS;
      #pragma unroll
      for (int ks = 0; ks < NKS; ++ks) {
        const f16x8 b = *(const f16x8*)(Wpk + (((size_t)(kcBase + ks) * 4 + wo) * 64 + lane) * 8);
        const f16x8 af = tav * a[ks];
        acc = __builtin_amdgcn_mfma_f32_32x32x16_f16(af, b, acc, 0, 0, 0);
      }
    }

    float* dst = part + (size_t)sk * Msz * 128;
    const int ocol = wo * 32 + l31;
    #pragma unroll
    for (int r = 0; r < 16; ++r) {
      const int mrow = m0 + wm * 32 + (r & 3) + 8 * (r >> 2) + 4 * lg;
      dst[(size_t)mrow * 128 + ocol] = acc[r];
    }
  }
}

// ---------------- split-K reduce + bias + tanh (float4) ----------------
template<bool TO_HPK>
__global__ __launch_bounds__(256) void k_red(
    const float* __restrict__ part, const float* __restrict__ bias,
    _Float16* __restrict__ hpk, float* __restrict__ spc)
{
  const int u  = blockIdx.x * 256 + threadIdx.x;   // 65536 units x 4 elems
  const int e4 = u * 4;
  const int m = e4 >> 7, p = e4 & 127;
  for (int rep = 0; rep < REP; ++rep) {
    asm volatile("" ::: "memory");
    float4 bv = *(const float4*)(bias + p);
    float4 s = bv;
    #pragma unroll
    for (int sk = 0; sk < SPLITK; sk++) {
      float4 v = *(const float4*)(part + (size_t)sk * (Msz * 128) + e4);
      s.x += v.x; s.y += v.y; s.z += v.z; s.w += v.w;
    }
    s.x = tanhf(s.x); s.y = tanhf(s.y); s.z = tanhf(s.z); s.w = tanhf(s.w);
    if (TO_HPK) {
      f16x4 h4 = {(_Float16)s.x, (_Float16)s.y, (_Float16)s.z, (_Float16)s.w};
      *(f16x4*)(hpk + ((size_t)(p >> 3) * Msz + m) * 8 + (p & 7)) = h4;
    } else {
      *(float4*)(spc + e4) = s;
    }
  }
}

// ---------------- finalize: gather over j with head[b,j]==i ----------------
__global__ __launch_bounds__(128) void k_finalize(
    const float* __restrict__ special,  // [Msz][128]
    const int*   __restrict__ heads,    // [Bsz][Ssz]
    const float* __restrict__ wred,     // [Ssz]
    const float* __restrict__ bred,     // [1]
    const float* __restrict__ bcomp,    // [128]
    float* __restrict__ out)            // [Bsz][Ssz][128]
{
  int b = blockIdx.x >> 8;
  int i = blockIdx.x & 255;
  int t = threadIdx.x;
  __shared__ float wr_s[Ssz];
  __shared__ int   hd_s[Ssz];
  wr_s[t]       = wred[t];
  wr_s[t + 128] = wred[t + 128];
  hd_s[t]       = heads[b * Ssz + t];
  hd_s[t + 128] = heads[b * Ssz + t + 128];
  __syncthreads();

  const float base  = tanhf(bcomp[t]);
  const float bred0 = bred[0];
  for (int rep = 0; rep < REP; ++rep) {
    asm volatile("" ::: "memory");
    float swr = 0.f, accv = 0.f;
    #pragma unroll 1
    for (int j = 0; j < Ssz; j++) {
      swr += wr_s[j];
      if (hd_s[j] == i)
        accv += wr_s[j] * (special[((size_t)b * Ssz + j) * 128 + t] - base);
    }
    out[((size_t)b * Ssz + i) * 128 + t] = base * swr + bred0 + accv;
  }
}

extern "C" void kernel_launch(void* const* d_in, const int* in_sizes, int n_in,
                              void* d_out, int out_size, void* d_ws, size_t ws_size,
                              hipStream_t stream) {
  const float* tok   = (const float*)d_in[0];
  const float* dep   = (const float*)d_in[1];
  const int*   hds   = (const int*)  d_in[2];
  const float* Wdep  = (const float*)d_in[3];
  const float* bdep  = (const float*)d_in[4];
  const float* Wcomp = (const float*)d_in[5];
  const float* bcomp = (const float*)d_in[6];
  const float* Wred  = (const float*)d_in[7];
  const float* bred  = (const float*)d_in[8];
  float* out = (float*)d_out;

  char* ws = (char*)d_ws;
  _Float16* W1pk = (_Float16*)(ws);                 // 2 MB
  _Float16* W2pk = (_Float16*)(ws + (2u  << 20));   // 4 MB
  _Float16* dpk  = (_Float16*)(ws + (6u  << 20));   // 256 KB
  _Float16* tokT = (_Float16*)(ws + (7u  << 20));   // 512 KB
  _Float16* hpk  = (_Float16*)(ws + (8u  << 20));   // 512 KB
  float*    part = (float*)   (ws + (9u  << 20));   // 8 MB (SPLITK=8)
  float*    spc  = (float*)   (ws + (18u << 20));   // 1 MB

  k_pack<<<1088, 256, 0, stream>>>(Wdep, Wcomp, dep, tok, W1pk, W2pk, dpk, tokT);

  // Phase 1: K=8192, KC=1024, Dv=64. 32 mb x 8 sk = 256 blocks, 512 thr.
  k_gemm<6, 1024><<<256, 512, 0, stream>>>(dpk, W1pk, tokT, part);
  k_red<true><<<256, 256, 0, stream>>>(part, bdep, hpk, nullptr);

  // Phase 2: K=16384, KC=2048, Dv=128.
  k_gemm<7, 2048><<<256, 512, 0, stream>>>(hpk, W2pk, tokT, part);
  k_red<false><<<256, 256, 0, stream>>>(part, bcomp, nullptr, spc);

  k_finalize<<<dim3(Bsz * Ssz), 128, 0, stream>>>(spc, hds, Wred, bred, bcomp, out);
}

// Round 9
// 73.101 us; speedup vs baseline: 19.3850x; 19.3850x over previous
//
#include <hip/hip_runtime.h>
#include <cstdint>
#include <cstddef>

#define Bsz 8
#define Ssz 256
#define Msz 2048
#define SPLITK 16

typedef _Float16 f16x8 __attribute__((ext_vector_type(8)));
typedef _Float16 f16x4 __attribute__((ext_vector_type(4)));
typedef float f32x16 __attribute__((ext_vector_type(16)));

// ---------------- one-time pack ----------------
// W1 [128][8192] f32  -> W1pk [512 kc][4 pb][64 lane][8] f16
// W2 [128][16384] f32 -> W2pk [1024][4][64][8] f16
// dep [2048][64] f32  -> dpk  [8 pc][2048 m][8] f16
// tok [2048][128] f32 -> tokT [128 t][2048 m] f16
__global__ __launch_bounds__(256) void k_pack(
    const float* __restrict__ W1, const float* __restrict__ W2,
    const float* __restrict__ dep, const float* __restrict__ tok,
    _Float16* __restrict__ W1pk, _Float16* __restrict__ W2pk,
    _Float16* __restrict__ dpk,  _Float16* __restrict__ tokT)
{
  __shared__ float tile[32][33];
  const int bx = blockIdx.x, tid = threadIdx.x;
  if (bx < 768) {
    const bool isW1 = bx < 256;
    const int idx = (isW1 ? bx : bx - 256) * 256 + tid;
    const int r  = idx & 31;
    const int pb = (idx >> 5) & 3;
    const int kc = idx >> 7;
    const float* src = (isW1 ? W1 : W2) + (size_t)(pb * 32 + r) * (isW1 ? 8192 : 16384) + kc * 16;
    const float4* s4 = (const float4*)src;
    float4 u0 = s4[0], u1 = s4[1], u2 = s4[2], u3 = s4[3];
    f16x8 lo = {(_Float16)u0.x,(_Float16)u0.y,(_Float16)u0.z,(_Float16)u0.w,
                (_Float16)u1.x,(_Float16)u1.y,(_Float16)u1.z,(_Float16)u1.w};
    f16x8 hi = {(_Float16)u2.x,(_Float16)u2.y,(_Float16)u2.z,(_Float16)u2.w,
                (_Float16)u3.x,(_Float16)u3.y,(_Float16)u3.z,(_Float16)u3.w};
    _Float16* dst = (isW1 ? W1pk : W2pk) + ((size_t)(kc * 4 + pb) * 64) * 8;
    *(f16x8*)(dst + (size_t)r * 8)        = lo;
    *(f16x8*)(dst + (size_t)(32 + r) * 8) = hi;
  } else if (bx < 832) {
    const int idx = (bx - 768) * 256 + tid;
    const int m = idx & 2047, pc = idx >> 11;
    const float4* s4 = (const float4*)(dep + (size_t)m * 64 + pc * 8);
    float4 u0 = s4[0], u1 = s4[1];
    f16x8 v = {(_Float16)u0.x,(_Float16)u0.y,(_Float16)u0.z,(_Float16)u0.w,
               (_Float16)u1.x,(_Float16)u1.y,(_Float16)u1.z,(_Float16)u1.w};
    *(f16x8*)(dpk + ((size_t)pc * Msz + m) * 8) = v;
  } else {
    const int q = bx - 832;
    const int mt = q >> 2, tt = q & 3;
    const int tx = tid & 31, ty = tid >> 5;
    for (int yy = ty; yy < 32; yy += 8)
      tile[yy][tx] = tok[(size_t)(mt * 32 + yy) * 128 + tt * 32 + tx];
    __syncthreads();
    for (int yy = ty; yy < 32; yy += 8)
      tokT[(size_t)(tt * 32 + yy) * Msz + mt * 32 + tx] = (_Float16)tile[tx][yy];
  }
}

// ---------------- MFMA GEMM: 64m x 128n block, 8 waves (2wm x 4wo), SPLITK=16 ----------------
// All tokT values hoisted (kills per-t-step dependent scalar-load stall); t-loop fully
// unrolled for static tr[] indexing. 512 blocks = 2/CU, launch_bounds(512,4) -> VGPR<=128
// -> 4 waves/SIMD co-resident.
// mfma_f32_32x32x16_f16: A row=lane&31, k=(lane>>5)*8+j; B col same; D col=lane&31,
// row=(reg&3)+8*(reg>>2)+4*(lane>>5).
template<int LGDV, int KC>
__global__ __launch_bounds__(512, 4) void k_gemm(
    const _Float16* __restrict__ Apk,   // [DV/8][Msz][8]
    const _Float16* __restrict__ Wpk,   // [Ktot/16][4][64][8]
    const _Float16* __restrict__ tokT,  // [128][Msz]
    float* __restrict__ part)           // [SPLITK][Msz][128]
{
  constexpr int DV  = 1 << LGDV;
  constexpr int NT  = KC >> LGDV;      // 8
  constexpr int NKS = DV >> 4;         // 4 (phase1) or 8 (phase2)

  const int tid  = threadIdx.x;
  const int lane = tid & 63;
  const int wv   = tid >> 6;           // 0..7
  const int wm   = wv >> 2;            // m-half (32 rows)
  const int wo   = wv & 3;             // n-quarter (32 cols)
  const int l31  = lane & 31;
  const int lg   = lane >> 5;
  const int id   = blockIdx.x;
  const int sk   = (id & 7) + 8 * (id >> 8);   // same-XCD blocks share sk -> W slice L2-resident
  const int mb   = (id >> 3) & 31;
  const int m0   = mb * 64;
  const int mrow0 = m0 + wm * 32 + l31;

  // hoist A fragments (invariant across t)
  f16x8 a[NKS];
  #pragma unroll
  for (int ks = 0; ks < NKS; ++ks)
    a[ks] = *(const f16x8*)(Apk + ((size_t)(ks * 2 + lg) * Msz + mrow0) * 8);

  // hoist tokT for all NT t's (breaks the per-t-step load->pk_mul->MFMA chain)
  const int t0 = sk * NT;
  _Float16 tr[NT];
  #pragma unroll
  for (int i = 0; i < NT; ++i)
    tr[i] = tokT[(size_t)(t0 + i) * Msz + mrow0];

  f32x16 acc = {};
  const int kc0 = sk * (KC >> 4);

  #pragma unroll
  for (int tg = 0; tg < NT; ++tg) {
    const _Float16 ta = tr[tg];
    const f16x8 tav = {ta,ta,ta,ta,ta,ta,ta,ta};
    #pragma unroll
    for (int ks = 0; ks < NKS; ++ks) {
      const f16x8 b = *(const f16x8*)(Wpk + (((size_t)(kc0 + tg * NKS + ks) * 4 + wo) * 64 + lane) * 8);
      const f16x8 af = tav * a[ks];
      acc = __builtin_amdgcn_mfma_f32_32x32x16_f16(af, b, acc, 0, 0, 0);
    }
  }

  float* dst = part + (size_t)sk * Msz * 128;
  const int ocol = wo * 32 + l31;
  #pragma unroll
  for (int r = 0; r < 16; ++r) {
    const int mrow = m0 + wm * 32 + (r & 3) + 8 * (r >> 2) + 4 * lg;
    dst[(size_t)mrow * 128 + ocol] = acc[r];
  }
}

// ---------------- split-K reduce + bias + tanh (float4) ----------------
template<bool TO_HPK>
__global__ __launch_bounds__(256) void k_red(
    const float* __restrict__ part, const float* __restrict__ bias,
    _Float16* __restrict__ hpk, float* __restrict__ spc)
{
  const int u  = blockIdx.x * 256 + threadIdx.x;   // 65536 units x 4 elems
  const int e4 = u * 4;
  const int m = e4 >> 7, p = e4 & 127;
  float4 s = *(const float4*)(bias + p);
  #pragma unroll
  for (int sk = 0; sk < SPLITK; sk++) {
    float4 v = *(const float4*)(part + (size_t)sk * (Msz * 128) + e4);
    s.x += v.x; s.y += v.y; s.z += v.z; s.w += v.w;
  }
  s.x = tanhf(s.x); s.y = tanhf(s.y); s.z = tanhf(s.z); s.w = tanhf(s.w);
  if (TO_HPK) {
    f16x4 h4 = {(_Float16)s.x, (_Float16)s.y, (_Float16)s.z, (_Float16)s.w};
    *(f16x4*)(hpk + ((size_t)(p >> 3) * Msz + m) * 8 + (p & 7)) = h4;
  } else {
    *(float4*)(spc + e4) = s;
  }
}

// ---------------- finalize: gather over j with head[b,j]==i ----------------
__global__ __launch_bounds__(128) void k_finalize(
    const float* __restrict__ special,  // [Msz][128]
    const int*   __restrict__ heads,    // [Bsz][Ssz]
    const float* __restrict__ wred,     // [Ssz]
    const float* __restrict__ bred,     // [1]
    const float* __restrict__ bcomp,    // [128]
    float* __restrict__ out)            // [Bsz][Ssz][128]
{
  int b = blockIdx.x >> 8;
  int i = blockIdx.x & 255;
  int t = threadIdx.x;
  __shared__ float wr_s[Ssz];
  __shared__ int   hd_s[Ssz];
  wr_s[t]       = wred[t];
  wr_s[t + 128] = wred[t + 128];
  hd_s[t]       = heads[b * Ssz + t];
  hd_s[t + 128] = heads[b * Ssz + t + 128];
  __syncthreads();

  const float base  = tanhf(bcomp[t]);
  const float bred0 = bred[0];
  float swr = 0.f, accv = 0.f;
  #pragma unroll 1
  for (int j = 0; j < Ssz; j++) {
    swr += wr_s[j];
    if (hd_s[j] == i)
      accv += wr_s[j] * (special[((size_t)b * Ssz + j) * 128 + t] - base);
  }
  out[((size_t)b * Ssz + i) * 128 + t] = base * swr + bred0 + accv;
}

extern "C" void kernel_launch(void* const* d_in, const int* in_sizes, int n_in,
                              void* d_out, int out_size, void* d_ws, size_t ws_size,
                              hipStream_t stream) {
  const float* tok   = (const float*)d_in[0];
  const float* dep   = (const float*)d_in[1];
  const int*   hds   = (const int*)  d_in[2];
  const float* Wdep  = (const float*)d_in[3];
  const float* bdep  = (const float*)d_in[4];
  const float* Wcomp = (const float*)d_in[5];
  const float* bcomp = (const float*)d_in[6];
  const float* Wred  = (const float*)d_in[7];
  const float* bred  = (const float*)d_in[8];
  float* out = (float*)d_out;

  char* ws = (char*)d_ws;
  _Float16* W1pk = (_Float16*)(ws);                 // 2 MB
  _Float16* W2pk = (_Float16*)(ws + (2u  << 20));   // 4 MB
  _Float16* dpk  = (_Float16*)(ws + (6u  << 20));   // 256 KB
  _Float16* tokT = (_Float16*)(ws + (7u  << 20));   // 512 KB
  _Float16* hpk  = (_Float16*)(ws + (8u  << 20));   // 512 KB
  float*    part = (float*)   (ws + (9u  << 20));   // 16 MB (SPLITK=16)
  float*    spc  = (float*)   (ws + (25u << 20));   // 1 MB

  k_pack<<<1088, 256, 0, stream>>>(Wdep, Wcomp, dep, tok, W1pk, W2pk, dpk, tokT);

  // Phase 1: K=8192, KC=512, Dv=64. 32 mb x 16 sk = 512 blocks, 512 thr.
  k_gemm<6, 512><<<512, 512, 0, stream>>>(dpk, W1pk, tokT, part);
  k_red<true><<<256, 256, 0, stream>>>(part, bdep, hpk, nullptr);

  // Phase 2: K=16384, KC=1024, Dv=128.
  k_gemm<7, 1024><<<512, 512, 0, stream>>>(hpk, W2pk, tokT, part);
  k_red<false><<<256, 256, 0, stream>>>(part, bcomp, nullptr, spc);

  k_finalize<<<dim3(Bsz * Ssz), 128, 0, stream>>>(spc, hds, Wred, bred, bcomp, out);
}